// Round 1
// baseline (36.039 us; speedup 1.0000x reference)
//
#include <hip/hip_runtime.h>

#define N 768
#define H 128
#define NM1 767

// ---------------- Phase 1: U = z @ W1a^T ; Vb = z @ W1b^T + b1 ----------------
#define P1_ROWS 4
__global__ __launch_bounds__(256) void p1_kernel(
    const float* __restrict__ z, const float* __restrict__ W1,
    const float* __restrict__ b1, float* __restrict__ U, float* __restrict__ Vb) {
  __shared__ __align__(16) float zsh[P1_ROWS][H];
  const int t = threadIdx.x;
  const int rbase = blockIdx.x * P1_ROWS;
  if (t < P1_ROWS * (H / 4)) {
    const int r = t >> 5, c4 = t & 31;
    ((float4*)zsh[r])[c4] = ((const float4*)(z + (size_t)(rbase + r) * H))[c4];
  }
  __syncthreads();
  const int half = t >> 7;          // 0 -> U column, 1 -> Vb column
  const int kc = t & (H - 1);
  const float* wrow = W1 + (size_t)kc * (2 * H) + half * H;
  float acc[P1_ROWS] = {0.f, 0.f, 0.f, 0.f};
#pragma unroll
  for (int m = 0; m < H; m += 4) {
    const float4 w = *(const float4*)(wrow + m);
#pragma unroll
    for (int r = 0; r < P1_ROWS; ++r) {
      const float4 zz = *(const float4*)&zsh[r][m];
      acc[r] = fmaf(w.x, zz.x, acc[r]);
      acc[r] = fmaf(w.y, zz.y, acc[r]);
      acc[r] = fmaf(w.z, zz.z, acc[r]);
      acc[r] = fmaf(w.w, zz.w, acc[r]);
    }
  }
  float* dst = half ? Vb : U;
  const float bias = half ? b1[kc] : 0.f;
#pragma unroll
  for (int r = 0; r < P1_ROWS; ++r)
    dst[(size_t)(rbase + r) * H + kc] = acc[r] + bias;
}

// ---------------- Phase 2: out[i,j] = sum_k relu(U[i,k]+Vb[j,k]) * w2[k] + b2 ----------------
#define TI 48
#define TJ 48
#define LDSW (H + 4)  // 132 floats: +4 pad => rows shift 4 banks, conflict-free b128 reads
__global__ __launch_bounds__(256) void p2_kernel(
    const float* __restrict__ U, const float* __restrict__ Vb,
    const float* __restrict__ w2, const float* __restrict__ b2,
    float* __restrict__ out) {
  __shared__ __align__(16) float ush[TI * LDSW];
  __shared__ __align__(16) float vsh[TJ * LDSW];
  const int t = threadIdx.x;
  const int bi = (blockIdx.x >> 4) * TI;
  const int bj = (blockIdx.x & 15) * TJ;
#pragma unroll
  for (int l = t; l < TI * (H / 4); l += 256) {
    const int r = l >> 5, c4 = l & 31;
    *(float4*)&ush[r * LDSW + c4 * 4] = ((const float4*)(U  + (size_t)(bi + r) * H))[c4];
    *(float4*)&vsh[r * LDSW + c4 * 4] = ((const float4*)(Vb + (size_t)(bj + r) * H))[c4];
  }
  __syncthreads();
  const int tx = t & 15, ty = t >> 4;
  float acc[3][3] = {};
#pragma unroll 4
  for (int k = 0; k < H; k += 4) {
    const float4 w = *(const float4*)(w2 + k);  // uniform -> s_load
    float4 uu[3], vv[3];
#pragma unroll
    for (int r = 0; r < 3; ++r) uu[r] = *(const float4*)&ush[(ty + 16 * r) * LDSW + k];
#pragma unroll
    for (int r = 0; r < 3; ++r) vv[r] = *(const float4*)&vsh[(tx + 16 * r) * LDSW + k];
#pragma unroll
    for (int a = 0; a < 3; ++a)
#pragma unroll
      for (int b = 0; b < 3; ++b) {
        acc[a][b] = fmaf(fmaxf(uu[a].x + vv[b].x, 0.f), w.x, acc[a][b]);
        acc[a][b] = fmaf(fmaxf(uu[a].y + vv[b].y, 0.f), w.y, acc[a][b]);
        acc[a][b] = fmaf(fmaxf(uu[a].z + vv[b].z, 0.f), w.z, acc[a][b]);
        acc[a][b] = fmaf(fmaxf(uu[a].w + vv[b].w, 0.f), w.w, acc[a][b]);
      }
  }
  const float bb = b2[0];
#pragma unroll
  for (int a = 0; a < 3; ++a) {
    const int i = bi + ty + 16 * a;
#pragma unroll
    for (int b = 0; b < 3; ++b) {
      const int j = bj + tx + 16 * b;
      if (i != j) out[(size_t)i * NM1 + j - (j > i ? 1 : 0)] = acc[a][b] + bb;
    }
  }
}

extern "C" void kernel_launch(void* const* d_in, const int* in_sizes, int n_in,
                              void* d_out, int out_size, void* d_ws, size_t ws_size,
                              hipStream_t stream) {
  const float* z  = (const float*)d_in[0];
  const float* W1 = (const float*)d_in[1];
  const float* b1 = (const float*)d_in[2];
  const float* W2 = (const float*)d_in[3];
  const float* b2 = (const float*)d_in[4];
  float* U  = (float*)d_ws;
  float* Vb = U + N * H;
  p1_kernel<<<N / P1_ROWS, 256, 0, stream>>>(z, W1, b1, U, Vb);
  p2_kernel<<<(N / TI) * (N / TJ), 256, 0, stream>>>(U, Vb, W2, b2, (float*)d_out);
}